// Round 8
// baseline (1237.284 us; speedup 1.0000x reference)
//
#include <hip/hip_runtime.h>
#include <hip/hip_bf16.h>
#include <math.h>

// Problem constants
#define BB 8
#define SS 1024
#define DD 512
#define HH 8
#define FF 2048
#define LL 6
#define HD 64
#define MM (BB * SS)      // 8192 rows
#define EPS 1e-6f
#define QKVS 1536         // fused QKV row stride

typedef __attribute__((ext_vector_type(8))) short bf16x8;
typedef __attribute__((ext_vector_type(4))) float f32x4;

typedef __attribute__((address_space(1))) const unsigned int g_u32;
typedef __attribute__((address_space(3))) unsigned int l_u32;

__device__ __forceinline__ short f2bf(float f) {
    union { float f; unsigned u; } c; c.f = f;
    unsigned u = c.u;
    u += 0x7fff + ((u >> 16) & 1);   // RNE
    return (short)(u >> 16);
}

__device__ __forceinline__ void gload_lds16(const void* g, void* l) {
    __builtin_amdgcn_global_load_lds((g_u32*)g, (l_u32*)l, 16, 0, 0);
}

// byte-address swizzle within a [rows][128B] LDS tile: XOR low+high row bits
// into the 16B-slot index so column-strided accesses spread across banks.
#define SWZB(row, cb) (((row) * 128) + ((cb) ^ ((((row) & 7) ^ (((row) >> 3) & 7)) << 4)))

// ---------------------------------------------------------------------------
// Kernel 1: embedding gather * sqrt(D) + sinusoidal positional encoding
// ---------------------------------------------------------------------------
__global__ __launch_bounds__(256) void embed_pe_kernel(
    const int* __restrict__ tokens, const float* __restrict__ emb,
    float* __restrict__ x)
{
    int idx = blockIdx.x * 256 + threadIdx.x;   // over B*S*D = 4M
    int d  = idx & (DD - 1);
    int bs = idx >> 9;                           // D = 512 = 2^9
    int s  = bs & (SS - 1);
    int tok = tokens[bs];
    float val = emb[(size_t)tok * DD + d] * 22.62741699796952f;  // sqrt(512)
    int i2 = d & ~1;
    float freq = expf((float)i2 * -0.017988946039015984f);  // -ln(10000)/512
    float ang = (float)s * freq;
    val += (d & 1) ? cosf(ang) : sinf(ang);
    x[idx] = val;
}

// ---------------------------------------------------------------------------
// Kernel 2: weight convert + transpose: W[K][N] fp32 -> Wt[N][K] bf16
// ---------------------------------------------------------------------------
__global__ __launch_bounds__(256) void wcvt_kernel(
    const float* __restrict__ W, short* __restrict__ Wt, int K, int N)
{
    __shared__ float tile[32][33];
    int n0 = blockIdx.x * 32, k0 = blockIdx.y * 32;
    int tx = threadIdx.x & 31, ty = threadIdx.x >> 5;   // 32 x 8
    #pragma unroll
    for (int i = 0; i < 4; ++i)
        tile[ty + i * 8][tx] = W[(size_t)(k0 + ty + i * 8) * N + n0 + tx];
    __syncthreads();
    #pragma unroll
    for (int i = 0; i < 4; ++i)
        Wt[(size_t)(n0 + ty + i * 8) * K + k0 + tx] = f2bf(tile[tx][ty + i * 8]);
}

// bias concat: [bq | bk | bv] -> bqkv[1536]
__global__ __launch_bounds__(256) void bcat_kernel(
    const float* __restrict__ bq, const float* __restrict__ bk,
    const float* __restrict__ bv, float* __restrict__ out)
{
    int i = blockIdx.x * 256 + threadIdx.x;
    float v = (i < 512) ? bq[i] : (i < 1024 ? bk[i - 512] : bv[i - 1024]);
    out[i] = v;
}

// ---------------------------------------------------------------------------
// Kernel 3: LayerNorm (unbiased std, eps added to std, scalar alpha/bias).
// fp32 in -> bf16 out. 2 rows per block, float4 loads, short4 stores.
// ---------------------------------------------------------------------------
__global__ __launch_bounds__(256) void ln_kernel(
    const float* __restrict__ x, short* __restrict__ y,
    const float* __restrict__ alpha_p, const float* __restrict__ beta_p)
{
    int t = threadIdx.x;
    int half = t >> 7, i = t & 127;
    int row = blockIdx.x * 2 + half;
    const float* xr = x + (size_t)row * DD;
    float4 v = *(const float4*)(xr + i * 4);

    __shared__ float red[8];
    float s = v.x + v.y + v.z + v.w;
    #pragma unroll
    for (int o = 32; o >= 1; o >>= 1) s += __shfl_xor(s, o, 64);
    int wv = t >> 6;
    if ((t & 63) == 0) red[wv] = s;
    __syncthreads();
    float mean = (red[half * 2] + red[half * 2 + 1]) * (1.0f / 512.0f);

    float d0 = v.x - mean, d1 = v.y - mean, d2 = v.z - mean, d3 = v.w - mean;
    float q = d0 * d0 + d1 * d1 + d2 * d2 + d3 * d3;
    #pragma unroll
    for (int o = 32; o >= 1; o >>= 1) q += __shfl_xor(q, o, 64);
    if ((t & 63) == 0) red[4 + wv] = q;
    __syncthreads();
    float var = (red[4 + half * 2] + red[5 + half * 2]) * (1.0f / 511.0f);
    float stdv = sqrtf(var);

    float alpha = alpha_p[0], beta = beta_p[0];
    float inv = alpha / (stdv + EPS);
    short4 ov;
    ov.x = f2bf(d0 * inv + beta); ov.y = f2bf(d1 * inv + beta);
    ov.z = f2bf(d2 * inv + beta); ov.w = f2bf(d3 * inv + beta);
    *(short4*)(y + (size_t)row * DD + i * 4) = ov;
}

// ---------------------------------------------------------------------------
// Kernel 4: bf16 MFMA GEMM  C[M,N] = A[M,K] @ Wt[N,K]^T + bias
// 2-phase double-buffered K-loop (T3-minimum): issue next tile's
// global_load_lds into the alternate LDS buffer BEFORE computing the current
// tile; one barrier per K-step (its vmcnt(0)+lgkmcnt(0) drain covers both
// the prefetch completion and all waves' reads of the current buffer).
// BM=128, BK=64, 4 waves. XCD-aware block swizzle (grids are %8==0).
// ---------------------------------------------------------------------------
template <int BN, bool RELU, bool RES, bool OUT_BF16>
__global__ __launch_bounds__(256) void gemm_mfma(
    const short* __restrict__ A, const short* __restrict__ Wt,
    const float* __restrict__ bias, const float* __restrict__ R,
    void* __restrict__ Cout, int M, int N, int K)
{
    __shared__ __align__(16) short As[2][128 * 64];   // [buf][m][k]
    __shared__ __align__(16) short Bs[2][BN * 64];    // [buf][n][k]

    constexpr int MI = (BN == 128) ? 4 : 2;
    constexpr int NI = 4;

    const int t = threadIdx.x;
    const int w = t >> 6, l = t & 63;
    const int l15 = l & 15, l4 = l >> 4;
    const int wrow = (BN == 128) ? (w >> 1) * 64 : w * 32;
    const int wcol = (BN == 128) ? (w & 1) * 64 : 0;

    // XCD swizzle: contiguous chunk of block-ids per XCD
    const int gx = gridDim.x;
    const int nwg = gx * gridDim.y;
    int id = blockIdx.y * gx + blockIdx.x;
    id = (id & 7) * (nwg >> 3) + (id >> 3);
    const int m0 = (id / gx) * 128, n0 = (id % gx) * BN;

    f32x4 acc[MI][NI];
    #pragma unroll
    for (int mi = 0; mi < MI; ++mi)
        #pragma unroll
        for (int ni = 0; ni < NI; ++ni) acc[mi][ni] = (f32x4){0.f, 0.f, 0.f, 0.f};

    const int lrow = l >> 3;            // 0..7
    const int lcol = (l & 7) * 8;       // shorts (16B per lane)

    auto stage = [&](int bufi, int k0) {
        #pragma unroll
        for (int i = 0; i < 4; ++i) {
            int r0 = (w * 4 + i) * 8;
            gload_lds16(A + (size_t)(m0 + r0 + lrow) * K + k0 + lcol,
                        &As[bufi][r0 * 64]);
        }
        #pragma unroll
        for (int i = 0; i < BN / 32; ++i) {
            int r0 = (w * (BN / 32) + i) * 8;
            gload_lds16(Wt + (size_t)(n0 + r0 + lrow) * K + k0 + lcol,
                        &Bs[bufi][r0 * 64]);
        }
    };

    const int NT = K >> 6;
    stage(0, 0);
    __syncthreads();                    // drains vmcnt(0): buf0 ready

    int cur = 0;
    for (int tix = 0; tix < NT; ++tix) {
        if (tix + 1 < NT) stage(cur ^ 1, (tix + 1) * 64);   // prefetch next

        #pragma unroll
        for (int ks = 0; ks < 2; ++ks) {
            bf16x8 af[MI], bf_[NI];
            #pragma unroll
            for (int mi = 0; mi < MI; ++mi)
                af[mi] = *(const bf16x8*)&As[cur][(wrow + mi * 16 + l15) * 64 + ks * 32 + l4 * 8];
            #pragma unroll
            for (int ni = 0; ni < NI; ++ni)
                bf_[ni] = *(const bf16x8*)&Bs[cur][(wcol + ni * 16 + l15) * 64 + ks * 32 + l4 * 8];
            #pragma unroll
            for (int mi = 0; mi < MI; ++mi)
                #pragma unroll
                for (int ni = 0; ni < NI; ++ni)
                    acc[mi][ni] = __builtin_amdgcn_mfma_f32_16x16x32_bf16(
                        af[mi], bf_[ni], acc[mi][ni], 0, 0, 0);
        }
        __syncthreads();                // prefetch landed + all reads of cur done
        cur ^= 1;
    }

    #pragma unroll
    for (int mi = 0; mi < MI; ++mi) {
        #pragma unroll
        for (int ni = 0; ni < NI; ++ni) {
            int col = n0 + wcol + ni * 16 + l15;
            float bcol = bias[col];
            #pragma unroll
            for (int r = 0; r < 4; ++r) {
                int row = m0 + wrow + mi * 16 + l4 * 4 + r;
                float c = acc[mi][ni][r] + bcol;
                if (RES)  c += R[(size_t)row * N + col];
                if (RELU) c = fmaxf(c, 0.0f);
                if (OUT_BF16) ((short*)Cout)[(size_t)row * N + col] = f2bf(c);
                else          ((float*)Cout)[(size_t)row * N + col] = c;
            }
        }
    }
}

// ---------------------------------------------------------------------------
// Kernel 5: MFMA bf16 flash attention, fused-QKV input [M][1536] bf16.
// Block = one (b,h) x 128 q-rows; 4 waves x 32 q-rows (256 thr). KVBLK = 64.
// Fixed-max softmax (shift-invariance; |scores| << 80 so exp cannot
// overflow; masked -> exp(-1e9) = 0): no running max, no O-rescale.
// K staged [key][d]; V transposed to [d][key] in registers (shfl_xor pair
// transpose + b32 writes). Row-sum of exp(S) via ones-B MFMA reusing PV
// A-frags. All LDS tiles SWZB-swizzled. setprio(1) around MFMA clusters
// (waves are phase-diverse between barriers -> scheduler can arbitrate).
// ---------------------------------------------------------------------------
__global__ __launch_bounds__(256) void attn_mfma_kernel(
    const short* __restrict__ qkv, const int* __restrict__ mask,
    short* __restrict__ o)
{
    __shared__ __align__(16) char Ks[64 * 128];      // [key][d]
    __shared__ __align__(16) char Vt[64 * 128];      // [d][key]
    __shared__ __align__(16) char Ps[4][32 * 128];   // per-wave P [q][key]

    const int qt = blockIdx.x;               // 0..7
    const int bh = blockIdx.y;               // 0..63
    const int b = bh >> 3, h = bh & 7;

    const int t = threadIdx.x;
    const int w = t >> 6;                    // wave 0..3
    const int l = t & 63;
    const int l15 = l & 15, l4 = l >> 4;
    const int l7 = l & 7,  l8 = l >> 3;

    const short* kb = qkv + ((size_t)b * SS) * QKVS + 512 + h * HD;
    const short* vb = qkv + ((size_t)b * SS) * QKVS + 1024 + h * HD;
    const int*   mb = mask + (size_t)b * SS;
    const int qbase = qt * 128 + w * 32;     // this wave's 32 q rows

    // Q fragments (A-layout): [qsub][kstep]
    bf16x8 qf[2][2];
    #pragma unroll
    for (int qs = 0; qs < 2; ++qs)
        #pragma unroll
        for (int ks = 0; ks < 2; ++ks)
            qf[qs][ks] = *(const bf16x8*)(qkv + ((size_t)b * SS + qbase + qs * 16 + l15) * QKVS
                                          + h * HD + ks * 32 + l4 * 8);

    bf16x8 onesv;
    #pragma unroll
    for (int j = 0; j < 8; ++j) onesv[j] = (short)0x3F80;   // bf16 1.0

    float l_run[2][4];
    f32x4 O[2][4];                           // [qsub][dsub]
    #pragma unroll
    for (int qs = 0; qs < 2; ++qs) {
        #pragma unroll
        for (int r = 0; r < 4; ++r) l_run[qs][r] = 0.0f;
        #pragma unroll
        for (int ds = 0; ds < 4; ++ds) O[qs][ds] = (f32x4){0.f, 0.f, 0.f, 0.f};
    }

    char* Pw = Ps[w];
    const int par = l & 1;
    const int kr = t >> 2;                   // K-stage row 0..63
    const int kc = (t & 3) * 32;             // K-stage col byte base

    for (int kt = 0; kt < SS / 64; ++kt) {
        // ---- stage K [key][d]: 2 x b128 per thread ----
        #pragma unroll
        for (int c = 0; c < 2; ++c) {
            bf16x8 kv = *(const bf16x8*)(kb + (size_t)(kt * 64 + kr) * QKVS + (t & 3) * 16 + 8 * c);
            *(bf16x8*)&Ks[SWZB(kr, kc + 16 * c)] = kv;
        }
        // ---- stage V^T via in-register pair transpose ----
        #pragma unroll
        for (int s = 0; s < 2; ++s) {
            int key = 16 * w + 8 * s + l7;
            int d0  = 8 * l8;
            int4 vv = *(const int4*)(vb + (size_t)(kt * 64 + key) * QKVS + d0);
            int p0 = __shfl_xor(vv.x, 1, 64);
            int p1 = __shfl_xor(vv.y, 1, 64);
            int p2 = __shfl_xor(vv.z, 1, 64);
            int p3 = __shfl_xor(vv.w, 1, 64);
            int cb = (key & ~1) * 2;
            int v0 = par ? (int)(((unsigned)p0 >> 16) | (vv.x & 0xFFFF0000))
                         : ((vv.x & 0xFFFF) | (p0 << 16));
            int v1 = par ? (int)(((unsigned)p1 >> 16) | (vv.y & 0xFFFF0000))
                         : ((vv.y & 0xFFFF) | (p1 << 16));
            int v2 = par ? (int)(((unsigned)p2 >> 16) | (vv.z & 0xFFFF0000))
                         : ((vv.z & 0xFFFF) | (p2 << 16));
            int v3 = par ? (int)(((unsigned)p3 >> 16) | (vv.w & 0xFFFF0000))
                         : ((vv.w & 0xFFFF) | (p3 << 16));
            *(int*)&Vt[SWZB(d0 + 0 + par, cb)] = v0;
            *(int*)&Vt[SWZB(d0 + 2 + par, cb)] = v1;
            *(int*)&Vt[SWZB(d0 + 4 + par, cb)] = v2;
            *(int*)&Vt[SWZB(d0 + 6 + par, cb)] = v3;
        }
        __syncthreads();

        // ---- S = Q @ K^T ----
        f32x4 S[2][4];                        // [qsub][ksub]
        #pragma unroll
        for (int qs = 0; qs < 2; ++qs)
            #pragma unroll
            for (int ku = 0; ku < 4; ++ku) S[qs][ku] = (f32x4){0.f, 0.f, 0.f, 0.f};
        __builtin_amdgcn_s_setprio(1);
        #pragma unroll
        for (int ks = 0; ks < 2; ++ks) {
            bf16x8 kf[4];
            #pragma unroll
            for (int ku = 0; ku < 4; ++ku)
                kf[ku] = *(const bf16x8*)&Ks[SWZB(ku * 16 + l15, ks * 64 + l4 * 16)];
            #pragma unroll
            for (int qs = 0; qs < 2; ++qs)
                #pragma unroll
                for (int ku = 0; ku < 4; ++ku)
                    S[qs][ku] = __builtin_amdgcn_mfma_f32_16x16x32_bf16(
                        qf[qs][ks], kf[ku], S[qs][ku], 0, 0, 0);
        }
        __builtin_amdgcn_s_setprio(0);

        // ---- softmax numerator: p = exp(s/8), masked -> 0 ----
        int mv[4];
        #pragma unroll
        for (int ku = 0; ku < 4; ++ku) mv[ku] = mb[kt * 64 + ku * 16 + l15];

        // ---- P (bf16) -> per-wave LDS [q][key] ----
        #pragma unroll
        for (int qs = 0; qs < 2; ++qs)
            #pragma unroll
            for (int ku = 0; ku < 4; ++ku)
                #pragma unroll
                for (int r = 0; r < 4; ++r) {
                    float sv = (mv[ku] == 0) ? -1e9f : S[qs][ku][r] * 0.125f;
                    *(short*)&Pw[SWZB(qs * 16 + l4 * 4 + r, (ku * 16 + l15) * 2)]
                        = f2bf(__expf(sv));
                }

        // ---- A-frags of P; rowsum via ones-MFMA; PV ----
        __builtin_amdgcn_s_setprio(1);
        #pragma unroll
        for (int qs = 0; qs < 2; ++qs) {
            bf16x8 pf[2];
            #pragma unroll
            for (int ks = 0; ks < 2; ++ks)
                pf[ks] = *(const bf16x8*)&Pw[SWZB(qs * 16 + l15, ks * 64 + l4 * 16)];

            f32x4 rs = (f32x4){0.f, 0.f, 0.f, 0.f};
            rs = __builtin_amdgcn_mfma_f32_16x16x32_bf16(pf[0], onesv, rs, 0, 0, 0);
            rs = __builtin_amdgcn_mfma_f32_16x16x32_bf16(pf[1], onesv, rs, 0, 0, 0);
            #pragma unroll
            for (int r = 0; r < 4; ++r) l_run[qs][r] += rs[r];

            #pragma unroll
            for (int ks = 0; ks < 2; ++ks) {
                bf16x8 vf[4];
                #pragma unroll
                for (int ds = 0; ds < 4; ++ds)
                    vf[ds] = *(const bf16x8*)&Vt[SWZB(ds * 16 + l15, ks * 64 + l4 * 16)];
                #pragma unroll
                for (int ds = 0; ds < 4; ++ds)
                    O[qs][ds] = __builtin_amdgcn_mfma_f32_16x16x32_bf16(
                        pf[ks], vf[ds], O[qs][ds], 0, 0, 0);
            }
        }
        __builtin_amdgcn_s_setprio(0);
        __syncthreads();   // before next tile overwrites Ks/Vt
    }

    // ---- epilogue: O / l_run -> bf16 ----
    #pragma unroll
    for (int qs = 0; qs < 2; ++qs)
        #pragma unroll
        for (int r = 0; r < 4; ++r) {
            float inv = 1.0f / l_run[qs][r];
            int qrow = qbase + qs * 16 + l4 * 4 + r;
            short* orow = o + ((size_t)b * SS + qrow) * DD + h * HD;
            #pragma unroll
            for (int ds = 0; ds < 4; ++ds)
                orow[ds * 16 + l15] = f2bf(O[qs][ds][r] * inv);
        }
}

// ---------------------------------------------------------------------------
// Host launcher
// ---------------------------------------------------------------------------
extern "C" void kernel_launch(void* const* d_in, const int* in_sizes, int n_in,
                              void* d_out, int out_size, void* d_ws, size_t ws_size,
                              hipStream_t stream)
{
    const int*   tokens = (const int*)  d_in[0];
    const int*   mask   = (const int*)  d_in[1];
    const float* emb    = (const float*)d_in[2];
    const float* Wq     = (const float*)d_in[3];
    const float* bq     = (const float*)d_in[4];
    const float* Wk     = (const float*)d_in[5];
    const float* bk     = (const float*)d_in[6];
    const float* Wv     = (const float*)d_in[7];
    const float* bv     = (const float*)d_in[8];
    const float* Wo     = (const float*)d_in[9];
    const float* bo     = (const float*)d_in[10];
    const float* W1     = (const float*)d_in[11];
    const float* b1     = (const float*)d_in[12];
    const float* W2     = (const float*)d_in[13];
    const float* b2     = (const float*)d_in[14];
    const float* ln_a1  = (const float*)d_in[15];
    const float* ln_b1  = (const float*)d_in[16];
    const float* ln_a2  = (const float*)d_in[17];
    const float* ln_b2  = (const float*)d_in[18];

    float* x = (float*)d_out;                 // residual stream fp32, in place

    // workspace layout (bytes)
    char* p = (char*)d_ws;
    short* qkv  = (short*)p;  p += (size_t)MM * QKVS * 2;    // 25.2 MB
    short* h    = (short*)p;  p += (size_t)MM * DD * 2;      // 8 MB
    short* ff   = (short*)p;  p += (size_t)MM * FF * 2;      // 32 MB
    short* Wqkvt= (short*)p;  p += (size_t)QKVS * DD * 2;    // 1.5 MB
    short* Wot  = (short*)p;  p += (size_t)DD * DD * 2;
    short* W1t  = (short*)p;  p += (size_t)FF * DD * 2;
    short* W2t  = (short*)p;  p += (size_t)DD * FF * 2;
    float* bqkv = (float*)p;  p += QKVS * 4;

    embed_pe_kernel<<<(MM * DD) / 256, 256, 0, stream>>>(tokens, emb, x);

    // one-time weight convert+transpose (runs every call; cheap)
    wcvt_kernel<<<dim3(DD / 32, DD / 32), 256, 0, stream>>>(Wq, Wqkvt,            DD, DD);
    wcvt_kernel<<<dim3(DD / 32, DD / 32), 256, 0, stream>>>(Wk, Wqkvt + 512*512,  DD, DD);
    wcvt_kernel<<<dim3(DD / 32, DD / 32), 256, 0, stream>>>(Wv, Wqkvt + 1024*512, DD, DD);
    wcvt_kernel<<<dim3(DD / 32, DD / 32), 256, 0, stream>>>(Wo, Wot, DD, DD);
    wcvt_kernel<<<dim3(FF / 32, DD / 32), 256, 0, stream>>>(W1, W1t, DD, FF);
    wcvt_kernel<<<dim3(DD / 32, FF / 32), 256, 0, stream>>>(W2, W2t, FF, DD);
    bcat_kernel<<<QKVS / 256, 256, 0, stream>>>(bq, bk, bv, bqkv);

    dim3 gQKV(QKVS / 128, MM / 128);   // 12 x 64 = 768 blocks
    dim3 gO  (DD / 64,    MM / 128);   // 8 x 64  = 512 blocks (BN=64)
    dim3 gF1 (FF / 128,   MM / 128);   // 16 x 64 = 1024 blocks
    dim3 gF2 (DD / 64,    MM / 128);   // 8 x 64  = 512 blocks (BN=64)
    dim3 gA  (SS / 128,   BB * HH);    // 8 x 64  = 512 blocks

    for (int layer = 0; layer < LL; ++layer) {
        // --- attention sublayer ---
        ln_kernel<<<MM / 2, 256, 0, stream>>>(x, h, ln_a1, ln_b1);
        gemm_mfma<128, false, false, true><<<gQKV, 256, 0, stream>>>(
            h, Wqkvt, bqkv, nullptr, qkv, MM, QKVS, DD);
        attn_mfma_kernel<<<gA, 256, 0, stream>>>(qkv, mask, h);
        gemm_mfma<64, false, true, false><<<gO, 256, 0, stream>>>(
            h, Wot, bo, x, x, MM, DD, DD);

        // --- feed-forward sublayer ---
        ln_kernel<<<MM / 2, 256, 0, stream>>>(x, h, ln_a2, ln_b2);
        gemm_mfma<128, true, false, true><<<gF1, 256, 0, stream>>>(
            h, W1t, b1, nullptr, ff, MM, FF, DD);
        gemm_mfma<64, false, true, false><<<gF2, 256, 0, stream>>>(
            ff, W2t, b2, x, x, MM, DD, FF);
    }
}

// Round 9
// 1199.385 us; speedup vs baseline: 1.0316x; 1.0316x over previous
//
#include <hip/hip_runtime.h>
#include <hip/hip_bf16.h>
#include <math.h>

// Problem constants
#define BB 8
#define SS 1024
#define DD 512
#define HH 8
#define FF 2048
#define LL 6
#define HD 64
#define MM (BB * SS)      // 8192 rows
#define EPS 1e-6f
#define QKVS 1536         // fused QKV row stride

typedef __attribute__((ext_vector_type(8))) short bf16x8;
typedef __attribute__((ext_vector_type(4))) float f32x4;

typedef __attribute__((address_space(1))) const unsigned int g_u32;
typedef __attribute__((address_space(3))) unsigned int l_u32;

__device__ __forceinline__ short f2bf(float f) {
    union { float f; unsigned u; } c; c.f = f;
    unsigned u = c.u;
    u += 0x7fff + ((u >> 16) & 1);   // RNE
    return (short)(u >> 16);
}

__device__ __forceinline__ void gload_lds16(const void* g, void* l) {
    __builtin_amdgcn_global_load_lds((g_u32*)g, (l_u32*)l, 16, 0, 0);
}

// byte-address swizzle within a [rows][128B] LDS tile: XOR low+high row bits
// into the 16B-slot index so column-strided accesses spread across banks.
#define SWZB(row, cb) (((row) * 128) + ((cb) ^ ((((row) & 7) ^ (((row) >> 3) & 7)) << 4)))

// ---------------------------------------------------------------------------
// Kernel 1: embedding gather * sqrt(D) + sinusoidal positional encoding
// ---------------------------------------------------------------------------
__global__ __launch_bounds__(256) void embed_pe_kernel(
    const int* __restrict__ tokens, const float* __restrict__ emb,
    float* __restrict__ x)
{
    int idx = blockIdx.x * 256 + threadIdx.x;   // over B*S*D = 4M
    int d  = idx & (DD - 1);
    int bs = idx >> 9;                           // D = 512 = 2^9
    int s  = bs & (SS - 1);
    int tok = tokens[bs];
    float val = emb[(size_t)tok * DD + d] * 22.62741699796952f;  // sqrt(512)
    int i2 = d & ~1;
    float freq = expf((float)i2 * -0.017988946039015984f);  // -ln(10000)/512
    float ang = (float)s * freq;
    val += (d & 1) ? cosf(ang) : sinf(ang);
    x[idx] = val;
}

// ---------------------------------------------------------------------------
// Kernel 2: weight convert + transpose: W[K][N] fp32 -> Wt[N][K] bf16
// ---------------------------------------------------------------------------
__global__ __launch_bounds__(256) void wcvt_kernel(
    const float* __restrict__ W, short* __restrict__ Wt, int K, int N)
{
    __shared__ float tile[32][33];
    int n0 = blockIdx.x * 32, k0 = blockIdx.y * 32;
    int tx = threadIdx.x & 31, ty = threadIdx.x >> 5;   // 32 x 8
    #pragma unroll
    for (int i = 0; i < 4; ++i)
        tile[ty + i * 8][tx] = W[(size_t)(k0 + ty + i * 8) * N + n0 + tx];
    __syncthreads();
    #pragma unroll
    for (int i = 0; i < 4; ++i)
        Wt[(size_t)(n0 + ty + i * 8) * K + k0 + tx] = f2bf(tile[tx][ty + i * 8]);
}

// bias concat: [bq | bk | bv] -> bqkv[1536]
__global__ __launch_bounds__(256) void bcat_kernel(
    const float* __restrict__ bq, const float* __restrict__ bk,
    const float* __restrict__ bv, float* __restrict__ out)
{
    int i = blockIdx.x * 256 + threadIdx.x;
    float v = (i < 512) ? bq[i] : (i < 1024 ? bk[i - 512] : bv[i - 1024]);
    out[i] = v;
}

// ---------------------------------------------------------------------------
// Kernel 3: LayerNorm (unbiased std, eps added to std, scalar alpha/bias).
// fp32 in -> bf16 out. ONE ROW PER WAVE (4 rows/block): pure wave-shuffle
// reduction, no LDS, no __syncthreads. 8 floats/lane (2 x float4), one 16B
// bf16x8 store.
// ---------------------------------------------------------------------------
__global__ __launch_bounds__(256) void ln_kernel(
    const float* __restrict__ x, short* __restrict__ y,
    const float* __restrict__ alpha_p, const float* __restrict__ beta_p)
{
    int t = threadIdx.x;
    int wv = t >> 6, l = t & 63;
    int row = blockIdx.x * 4 + wv;
    const float* xr = x + (size_t)row * DD + l * 8;
    float4 a = *(const float4*)xr;
    float4 b = *(const float4*)(xr + 4);

    float v[8] = {a.x, a.y, a.z, a.w, b.x, b.y, b.z, b.w};
    float s = 0.0f;
    #pragma unroll
    for (int j = 0; j < 8; ++j) s += v[j];
    #pragma unroll
    for (int o = 32; o >= 1; o >>= 1) s += __shfl_xor(s, o, 64);
    float mean = s * (1.0f / 512.0f);

    float q = 0.0f;
    #pragma unroll
    for (int j = 0; j < 8; ++j) { v[j] -= mean; q += v[j] * v[j]; }
    #pragma unroll
    for (int o = 32; o >= 1; o >>= 1) q += __shfl_xor(q, o, 64);
    float stdv = sqrtf(q * (1.0f / 511.0f));

    float alpha = alpha_p[0], beta = beta_p[0];
    float inv = alpha / (stdv + EPS);
    bf16x8 ov;
    #pragma unroll
    for (int j = 0; j < 8; ++j) ov[j] = f2bf(v[j] * inv + beta);
    *(bf16x8*)(y + (size_t)row * DD + l * 8) = ov;
}

// ---------------------------------------------------------------------------
// Kernel 4: bf16 MFMA GEMM  C[M,N] = A[M,K] @ Wt[N,K]^T + bias
// 2-phase double-buffered K-loop: issue next tile's global_load_lds into the
// alternate LDS buffer BEFORE computing the current tile; one barrier per
// K-step. BM=128, BK=64, 4 waves. XCD-aware block swizzle (grids %8==0).
// ---------------------------------------------------------------------------
template <int BN, bool RELU, bool RES, bool OUT_BF16>
__global__ __launch_bounds__(256) void gemm_mfma(
    const short* __restrict__ A, const short* __restrict__ Wt,
    const float* __restrict__ bias, const float* __restrict__ R,
    void* __restrict__ Cout, int M, int N, int K)
{
    __shared__ __align__(16) short As[2][128 * 64];   // [buf][m][k]
    __shared__ __align__(16) short Bs[2][BN * 64];    // [buf][n][k]

    constexpr int MI = (BN == 128) ? 4 : 2;
    constexpr int NI = 4;

    const int t = threadIdx.x;
    const int w = t >> 6, l = t & 63;
    const int l15 = l & 15, l4 = l >> 4;
    const int wrow = (BN == 128) ? (w >> 1) * 64 : w * 32;
    const int wcol = (BN == 128) ? (w & 1) * 64 : 0;

    // XCD swizzle: contiguous chunk of block-ids per XCD
    const int gx = gridDim.x;
    const int nwg = gx * gridDim.y;
    int id = blockIdx.y * gx + blockIdx.x;
    id = (id & 7) * (nwg >> 3) + (id >> 3);
    const int m0 = (id / gx) * 128, n0 = (id % gx) * BN;

    f32x4 acc[MI][NI];
    #pragma unroll
    for (int mi = 0; mi < MI; ++mi)
        #pragma unroll
        for (int ni = 0; ni < NI; ++ni) acc[mi][ni] = (f32x4){0.f, 0.f, 0.f, 0.f};

    const int lrow = l >> 3;            // 0..7
    const int lcol = (l & 7) * 8;       // shorts (16B per lane)

    auto stage = [&](int bufi, int k0) {
        #pragma unroll
        for (int i = 0; i < 4; ++i) {
            int r0 = (w * 4 + i) * 8;
            gload_lds16(A + (size_t)(m0 + r0 + lrow) * K + k0 + lcol,
                        &As[bufi][r0 * 64]);
        }
        #pragma unroll
        for (int i = 0; i < BN / 32; ++i) {
            int r0 = (w * (BN / 32) + i) * 8;
            gload_lds16(Wt + (size_t)(n0 + r0 + lrow) * K + k0 + lcol,
                        &Bs[bufi][r0 * 64]);
        }
    };

    const int NT = K >> 6;
    stage(0, 0);
    __syncthreads();                    // drains vmcnt(0): buf0 ready

    int cur = 0;
    for (int tix = 0; tix < NT; ++tix) {
        if (tix + 1 < NT) stage(cur ^ 1, (tix + 1) * 64);   // prefetch next

        #pragma unroll
        for (int ks = 0; ks < 2; ++ks) {
            bf16x8 af[MI], bf_[NI];
            #pragma unroll
            for (int mi = 0; mi < MI; ++mi)
                af[mi] = *(const bf16x8*)&As[cur][(wrow + mi * 16 + l15) * 64 + ks * 32 + l4 * 8];
            #pragma unroll
            for (int ni = 0; ni < NI; ++ni)
                bf_[ni] = *(const bf16x8*)&Bs[cur][(wcol + ni * 16 + l15) * 64 + ks * 32 + l4 * 8];
            #pragma unroll
            for (int mi = 0; mi < MI; ++mi)
                #pragma unroll
                for (int ni = 0; ni < NI; ++ni)
                    acc[mi][ni] = __builtin_amdgcn_mfma_f32_16x16x32_bf16(
                        af[mi], bf_[ni], acc[mi][ni], 0, 0, 0);
        }
        __syncthreads();                // prefetch landed + all reads of cur done
        cur ^= 1;
    }

    #pragma unroll
    for (int mi = 0; mi < MI; ++mi) {
        #pragma unroll
        for (int ni = 0; ni < NI; ++ni) {
            int col = n0 + wcol + ni * 16 + l15;
            float bcol = bias[col];
            #pragma unroll
            for (int r = 0; r < 4; ++r) {
                int row = m0 + wrow + mi * 16 + l4 * 4 + r;
                float c = acc[mi][ni][r] + bcol;
                if (RES)  c += R[(size_t)row * N + col];
                if (RELU) c = fmaxf(c, 0.0f);
                if (OUT_BF16) ((short*)Cout)[(size_t)row * N + col] = f2bf(c);
                else          ((float*)Cout)[(size_t)row * N + col] = c;
            }
        }
    }
}

// ---------------------------------------------------------------------------
// Kernel 5: MFMA bf16 flash attention, fused-QKV input [M][1536] bf16.
// Block = one (b,h) x 128 q-rows; 4 waves x 32 q-rows (256 thr). KVBLK = 64.
// Fixed-max softmax (shift-invariance; |scores| << 80): no running max.
// T14 async-STAGE: next tile's K/V global loads are issued right after the
// post-stage barrier, so HBM/L2 latency hides under this tile's compute;
// the reg->LDS write happens at the next iteration top.
// K staged [key][d]; V transposed to [d][key] in registers (shfl_xor pair
// transpose + b32 writes). Row-sum of exp(S) via ones-B MFMA. SWZB swizzle.
// NO setprio: waves here are barrier-lockstep (m190-null regime; r8 A/B
// showed setprio costs ~15% on this kernel).
// ---------------------------------------------------------------------------
__global__ __launch_bounds__(256) void attn_mfma_kernel(
    const short* __restrict__ qkv, const int* __restrict__ mask,
    short* __restrict__ o)
{
    __shared__ __align__(16) char Ks[64 * 128];      // [key][d]
    __shared__ __align__(16) char Vt[64 * 128];      // [d][key]
    __shared__ __align__(16) char Ps[4][32 * 128];   // per-wave P [q][key]

    const int qt = blockIdx.x;               // 0..7
    const int bh = blockIdx.y;               // 0..63
    const int b = bh >> 3, h = bh & 7;

    const int t = threadIdx.x;
    const int w = t >> 6;                    // wave 0..3
    const int l = t & 63;
    const int l15 = l & 15, l4 = l >> 4;
    const int l7 = l & 7,  l8 = l >> 3;

    const short* kb = qkv + ((size_t)b * SS) * QKVS + 512 + h * HD;
    const short* vb = qkv + ((size_t)b * SS) * QKVS + 1024 + h * HD;
    const int*   mb = mask + (size_t)b * SS;
    const int qbase = qt * 128 + w * 32;     // this wave's 32 q rows

    // Q fragments (A-layout): [qsub][kstep]
    bf16x8 qf[2][2];
    #pragma unroll
    for (int qs = 0; qs < 2; ++qs)
        #pragma unroll
        for (int ks = 0; ks < 2; ++ks)
            qf[qs][ks] = *(const bf16x8*)(qkv + ((size_t)b * SS + qbase + qs * 16 + l15) * QKVS
                                          + h * HD + ks * 32 + l4 * 8);

    bf16x8 onesv;
    #pragma unroll
    for (int j = 0; j < 8; ++j) onesv[j] = (short)0x3F80;   // bf16 1.0

    float l_run[2][4];
    f32x4 O[2][4];                           // [qsub][dsub]
    #pragma unroll
    for (int qs = 0; qs < 2; ++qs) {
        #pragma unroll
        for (int r = 0; r < 4; ++r) l_run[qs][r] = 0.0f;
        #pragma unroll
        for (int ds = 0; ds < 4; ++ds) O[qs][ds] = (f32x4){0.f, 0.f, 0.f, 0.f};
    }

    char* Pw = Ps[w];
    const int par = l & 1;
    const int kr  = t >> 2;                  // K-stage row 0..63
    const int kcs = (t & 3) * 16;            // K-stage col (shorts)
    const int vkey0 = 16 * w + l7;           // V-stage keys
    const int vkey1 = 16 * w + 8 + l7;
    const int vd0 = 8 * l8;

    // ---- prologue: tile 0 loads into regs ----
    bf16x8 kreg0 = *(const bf16x8*)(kb + (size_t)kr * QKVS + kcs);
    bf16x8 kreg1 = *(const bf16x8*)(kb + (size_t)kr * QKVS + kcs + 8);
    int4   vreg0 = *(const int4*)(vb + (size_t)vkey0 * QKVS + vd0);
    int4   vreg1 = *(const int4*)(vb + (size_t)vkey1 * QKVS + vd0);

    for (int kt = 0; kt < SS / 64; ++kt) {
        // ---- write stage: regs -> LDS ----
        *(bf16x8*)&Ks[SWZB(kr, kcs * 2)]      = kreg0;
        *(bf16x8*)&Ks[SWZB(kr, kcs * 2 + 16)] = kreg1;
        #pragma unroll
        for (int s = 0; s < 2; ++s) {
            int4 vv = s ? vreg1 : vreg0;
            int key = s ? vkey1 : vkey0;
            int p0 = __shfl_xor(vv.x, 1, 64);
            int p1 = __shfl_xor(vv.y, 1, 64);
            int p2 = __shfl_xor(vv.z, 1, 64);
            int p3 = __shfl_xor(vv.w, 1, 64);
            int cb = (key & ~1) * 2;
            int v0 = par ? (int)(((unsigned)p0 >> 16) | (vv.x & 0xFFFF0000))
                         : ((vv.x & 0xFFFF) | (p0 << 16));
            int v1 = par ? (int)(((unsigned)p1 >> 16) | (vv.y & 0xFFFF0000))
                         : ((vv.y & 0xFFFF) | (p1 << 16));
            int v2 = par ? (int)(((unsigned)p2 >> 16) | (vv.z & 0xFFFF0000))
                         : ((vv.z & 0xFFFF) | (p2 << 16));
            int v3 = par ? (int)(((unsigned)p3 >> 16) | (vv.w & 0xFFFF0000))
                         : ((vv.w & 0xFFFF) | (p3 << 16));
            *(int*)&Vt[SWZB(vd0 + 0 + par, cb)] = v0;
            *(int*)&Vt[SWZB(vd0 + 2 + par, cb)] = v1;
            *(int*)&Vt[SWZB(vd0 + 4 + par, cb)] = v2;
            *(int*)&Vt[SWZB(vd0 + 6 + par, cb)] = v3;
        }
        __syncthreads();

        // ---- T14: issue next tile's loads now (latency hides under compute) ----
        if (kt + 1 < SS / 64) {
            const short* kbn = kb + (size_t)((kt + 1) * 64) * QKVS;
            const short* vbn = vb + (size_t)((kt + 1) * 64) * QKVS;
            kreg0 = *(const bf16x8*)(kbn + (size_t)kr * QKVS + kcs);
            kreg1 = *(const bf16x8*)(kbn + (size_t)kr * QKVS + kcs + 8);
            vreg0 = *(const int4*)(vbn + (size_t)vkey0 * QKVS + vd0);
            vreg1 = *(const int4*)(vbn + (size_t)vkey1 * QKVS + vd0);
        }

        // ---- S = Q @ K^T ----
        f32x4 S[2][4];                        // [qsub][ksub]
        #pragma unroll
        for (int qs = 0; qs < 2; ++qs)
            #pragma unroll
            for (int ku = 0; ku < 4; ++ku) S[qs][ku] = (f32x4){0.f, 0.f, 0.f, 0.f};
        #pragma unroll
        for (int ks = 0; ks < 2; ++ks) {
            bf16x8 kf[4];
            #pragma unroll
            for (int ku = 0; ku < 4; ++ku)
                kf[ku] = *(const bf16x8*)&Ks[SWZB(ku * 16 + l15, ks * 64 + l4 * 16)];
            #pragma unroll
            for (int qs = 0; qs < 2; ++qs)
                #pragma unroll
                for (int ku = 0; ku < 4; ++ku)
                    S[qs][ku] = __builtin_amdgcn_mfma_f32_16x16x32_bf16(
                        qf[qs][ks], kf[ku], S[qs][ku], 0, 0, 0);
        }

        // ---- softmax numerator: p = exp(s/8), masked -> 0 ----
        int mv[4];
        #pragma unroll
        for (int ku = 0; ku < 4; ++ku) mv[ku] = mb[kt * 64 + ku * 16 + l15];

        // ---- P (bf16) -> per-wave LDS [q][key] ----
        #pragma unroll
        for (int qs = 0; qs < 2; ++qs)
            #pragma unroll
            for (int ku = 0; ku < 4; ++ku)
                #pragma unroll
                for (int r = 0; r < 4; ++r) {
                    float sv = (mv[ku] == 0) ? -1e9f : S[qs][ku][r] * 0.125f;
                    *(short*)&Pw[SWZB(qs * 16 + l4 * 4 + r, (ku * 16 + l15) * 2)]
                        = f2bf(__expf(sv));
                }

        // ---- A-frags of P; rowsum via ones-MFMA; PV ----
        #pragma unroll
        for (int qs = 0; qs < 2; ++qs) {
            bf16x8 pf[2];
            #pragma unroll
            for (int ks = 0; ks < 2; ++ks)
                pf[ks] = *(const bf16x8*)&Pw[SWZB(qs * 16 + l15, ks * 64 + l4 * 16)];

            f32x4 rs = (f32x4){0.f, 0.f, 0.f, 0.f};
            rs = __builtin_amdgcn_mfma_f32_16x16x32_bf16(pf[0], onesv, rs, 0, 0, 0);
            rs = __builtin_amdgcn_mfma_f32_16x16x32_bf16(pf[1], onesv, rs, 0, 0, 0);
            #pragma unroll
            for (int r = 0; r < 4; ++r) l_run[qs][r] += rs[r];

            #pragma unroll
            for (int ks = 0; ks < 2; ++ks) {
                bf16x8 vf[4];
                #pragma unroll
                for (int ds = 0; ds < 4; ++ds)
                    vf[ds] = *(const bf16x8*)&Vt[SWZB(ds * 16 + l15, ks * 64 + l4 * 16)];
                #pragma unroll
                for (int ds = 0; ds < 4; ++ds)
                    O[qs][ds] = __builtin_amdgcn_mfma_f32_16x16x32_bf16(
                        pf[ks], vf[ds], O[qs][ds], 0, 0, 0);
            }
        }
        __syncthreads();   // before next tile overwrites Ks/Vt
    }

    // ---- epilogue: O / l_run -> bf16 ----
    #pragma unroll
    for (int qs = 0; qs < 2; ++qs)
        #pragma unroll
        for (int r = 0; r < 4; ++r) {
            float inv = 1.0f / l_run[qs][r];
            int qrow = qbase + qs * 16 + l4 * 4 + r;
            short* orow = o + ((size_t)b * SS + qrow) * DD + h * HD;
            #pragma unroll
            for (int ds = 0; ds < 4; ++ds)
                orow[ds * 16 + l15] = f2bf(O[qs][ds][r] * inv);
        }
}

// ---------------------------------------------------------------------------
// Host launcher
// ---------------------------------------------------------------------------
extern "C" void kernel_launch(void* const* d_in, const int* in_sizes, int n_in,
                              void* d_out, int out_size, void* d_ws, size_t ws_size,
                              hipStream_t stream)
{
    const int*   tokens = (const int*)  d_in[0];
    const int*   mask   = (const int*)  d_in[1];
    const float* emb    = (const float*)d_in[2];
    const float* Wq     = (const float*)d_in[3];
    const float* bq     = (const float*)d_in[4];
    const float* Wk     = (const float*)d_in[5];
    const float* bk     = (const float*)d_in[6];
    const float* Wv     = (const float*)d_in[7];
    const float* bv     = (const float*)d_in[8];
    const float* Wo     = (const float*)d_in[9];
    const float* bo     = (const float*)d_in[10];
    const float* W1     = (const float*)d_in[11];
    const float* b1     = (const float*)d_in[12];
    const float* W2     = (const float*)d_in[13];
    const float* b2     = (const float*)d_in[14];
    const float* ln_a1  = (const float*)d_in[15];
    const float* ln_b1  = (const float*)d_in[16];
    const float* ln_a2  = (const float*)d_in[17];
    const float* ln_b2  = (const float*)d_in[18];

    float* x = (float*)d_out;                 // residual stream fp32, in place

    // workspace layout (bytes)
    char* p = (char*)d_ws;
    short* qkv  = (short*)p;  p += (size_t)MM * QKVS * 2;    // 25.2 MB
    short* h    = (short*)p;  p += (size_t)MM * DD * 2;      // 8 MB
    short* ff   = (short*)p;  p += (size_t)MM * FF * 2;      // 32 MB
    short* Wqkvt= (short*)p;  p += (size_t)QKVS * DD * 2;    // 1.5 MB
    short* Wot  = (short*)p;  p += (size_t)DD * DD * 2;
    short* W1t  = (short*)p;  p += (size_t)FF * DD * 2;
    short* W2t  = (short*)p;  p += (size_t)DD * FF * 2;
    float* bqkv = (float*)p;  p += QKVS * 4;

    embed_pe_kernel<<<(MM * DD) / 256, 256, 0, stream>>>(tokens, emb, x);

    // one-time weight convert+transpose (runs every call; cheap)
    wcvt_kernel<<<dim3(DD / 32, DD / 32), 256, 0, stream>>>(Wq, Wqkvt,            DD, DD);
    wcvt_kernel<<<dim3(DD / 32, DD / 32), 256, 0, stream>>>(Wk, Wqkvt + 512*512,  DD, DD);
    wcvt_kernel<<<dim3(DD / 32, DD / 32), 256, 0, stream>>>(Wv, Wqkvt + 1024*512, DD, DD);
    wcvt_kernel<<<dim3(DD / 32, DD / 32), 256, 0, stream>>>(Wo, Wot, DD, DD);
    wcvt_kernel<<<dim3(FF / 32, DD / 32), 256, 0, stream>>>(W1, W1t, DD, FF);
    wcvt_kernel<<<dim3(DD / 32, FF / 32), 256, 0, stream>>>(W2, W2t, FF, DD);
    bcat_kernel<<<QKVS / 256, 256, 0, stream>>>(bq, bk, bv, bqkv);

    dim3 gQKV(QKVS / 128, MM / 128);   // 12 x 64 = 768 blocks
    dim3 gO  (DD / 64,    MM / 128);   // 8 x 64  = 512 blocks (BN=64)
    dim3 gF1 (FF / 128,   MM / 128);   // 16 x 64 = 1024 blocks
    dim3 gF2 (DD / 64,    MM / 128);   // 8 x 64  = 512 blocks (BN=64)
    dim3 gA  (SS / 128,   BB * HH);    // 8 x 64  = 512 blocks

    for (int layer = 0; layer < LL; ++layer) {
        // --- attention sublayer ---
        ln_kernel<<<MM / 4, 256, 0, stream>>>(x, h, ln_a1, ln_b1);
        gemm_mfma<128, false, false, true><<<gQKV, 256, 0, stream>>>(
            h, Wqkvt, bqkv, nullptr, qkv, MM, QKVS, DD);
        attn_mfma_kernel<<<gA, 256, 0, stream>>>(qkv, mask, h);
        gemm_mfma<64, false, true, false><<<gO, 256, 0, stream>>>(
            h, Wot, bo, x, x, MM, DD, DD);

        // --- feed-forward sublayer ---
        ln_kernel<<<MM / 4, 256, 0, stream>>>(x, h, ln_a2, ln_b2);
        gemm_mfma<128, true, false, true><<<gF1, 256, 0, stream>>>(
            h, W1t, b1, nullptr, ff, MM, FF, DD);
        gemm_mfma<64, false, true, false><<<gF2, 256, 0, stream>>>(
            ff, W2t, b2, x, x, MM, DD, FF);
    }
}